// Round 2
// baseline (500.940 us; speedup 1.0000x reference)
//
#include <hip/hip_runtime.h>
#include <hip/hip_bf16.h>
#include <cstdint>

typedef __bf16 bf16;
typedef __bf16 bf16x8 __attribute__((ext_vector_type(8)));
typedef float f32x4 __attribute__((ext_vector_type(4)));
typedef int i32x4 __attribute__((ext_vector_type(4)));

#define HIDC 96
#define CINC 192
#define EPSC 1e-5f

// ---------------------------------------------------------------------------
// K0: repack W_conv [27][192][96] fp32 + W_lin [192][96] fp32 into bf16
// MFMA-B fragment order. dst layout: [off(28)][cix=kc*6+ct (36)][lane(64)][j(8)]
//   element = W[off][k = kc*32 + (lane>>4)*8 + j][col = ct*16 + (lane&15)]
// ---------------------------------------------------------------------------
__global__ void k_repack(const float* __restrict__ Wc, const float* __restrict__ Wl,
                         bf16* __restrict__ dst, int total) {
  int t = blockIdx.x * 256 + threadIdx.x;
  if (t >= total) return;
  int off = t / 18432;
  int rem = t - off * 18432;
  int cix = rem >> 9;
  int lane = (rem >> 3) & 63;
  int j = rem & 7;
  int k = (cix / 6) * 32 + ((lane >> 4) << 3) + j;
  int col = (cix % 6) * 16 + (lane & 15);
  const float* src = (off < 27) ? (Wc + ((size_t)off * CINC + k) * HIDC + col)
                                : (Wl + (size_t)k * HIDC + col);
  dst[t] = (bf16)(*src);
}

// ---------------------------------------------------------------------------
// K1: voxelize scatter-add (fp32 atomics). one thread per (point, channel).
// ---------------------------------------------------------------------------
__global__ void k_voxelize(const float* __restrict__ hid, const float* __restrict__ qry,
                           const int* __restrict__ seg, float* __restrict__ vsum,
                           float* __restrict__ cnt, int Npts) {
  int t = blockIdx.x * 256 + threadIdx.x;
  if (t >= Npts * CINC) return;
  int p = t / CINC;
  int c = t - p * CINC;
  float v = (c < HIDC) ? hid[(size_t)p * HIDC + c] : qry[(size_t)p * HIDC + c - HIDC];
  int s = seg[p];
  atomicAdd(vsum + (size_t)s * CINC + c, v);
  if (c == 0) atomicAdd(cnt + s, 1.0f);
}

// ---------------------------------------------------------------------------
// K2: vfeat = vsum / max(cnt,1) -> bf16, with zero pad row at index M.
// ---------------------------------------------------------------------------
__global__ void k_vfeat(const float* __restrict__ vsum, const float* __restrict__ cnt,
                        bf16* __restrict__ vpad, int M) {
  int t = blockIdx.x * 256 + threadIdx.x;
  if (t >= (M + 1) * CINC) return;
  int v = t / CINC;
  float x = 0.f;
  if (v < M) x = vsum[t] / fmaxf(cnt[v], 1.0f);
  vpad[t] = (bf16)x;
}

// ---------------------------------------------------------------------------
// K3: sparse conv. 384 threads = 6 waves; 64 rows/wave; 96 cols.
// A-frags gathered straight from global (16B/lane); B staged to LDS in
// half-offset (18KB) chunks, double buffered, register-prefetched, 1 barrier
// per stage. Epilogue: fp32 acc store + BN sum/sumsq atomics.
// ---------------------------------------------------------------------------
__launch_bounds__(384, 2)
__global__ void k_conv(const bf16* __restrict__ vpad, const int* __restrict__ nbr,
                       const bf16* __restrict__ wpack, float* __restrict__ accbuf,
                       float* __restrict__ bnsum, int M) {
  __shared__ bf16 Bb[2][9216];  // 2 x 18KB
  const int tid = threadIdx.x;
  const int wave = tid >> 6;
  const int lane = tid & 63;
  const int m = lane & 15;
  const int quad = lane >> 4;
  const int rb = blockIdx.x * 384 + wave * 64;

  f32x4 acc[4][6];
#pragma unroll
  for (int rt = 0; rt < 4; rt++)
#pragma unroll
    for (int ct = 0; ct < 6; ct++) {
      f32x4 z = {0.f, 0.f, 0.f, 0.f};
      acc[rt][ct] = z;
    }

  const char* wb = (const char*)wpack;
  const size_t lanestage = (size_t)(wave * 3) * 1024 + (size_t)lane * 16;
  i32x4 breg[3];
#pragma unroll
  for (int i = 0; i < 3; i++)
    breg[i] = *(const i32x4*)(wb + lanestage + (size_t)i * 1024);

  int gidx[4];
  for (int s = 0; s < 54; s++) {
    const int buf = s & 1;
    {
      char* bbw = (char*)&Bb[buf][0];
#pragma unroll
      for (int i = 0; i < 3; i++)
        *(i32x4*)(bbw + (size_t)(wave * 3 + i) * 1024 + (size_t)lane * 16) = breg[i];
    }
    __syncthreads();
    if (s + 1 < 54) {
      const char* src = wb + (size_t)(s + 1) * 18432 + lanestage;
#pragma unroll
      for (int i = 0; i < 3; i++)
        breg[i] = *(const i32x4*)(src + (size_t)i * 1024);
    }
    const int off = s >> 1;
    const int half = s & 1;
    if (half == 0) {
#pragma unroll
      for (int rt = 0; rt < 4; rt++) {
        int r = rb + rt * 16 + m;
        gidx[rt] = (r < M) ? nbr[(size_t)r * 27 + off] : M;  // row M = zero pad
      }
    }
    const char* bbr = (const char*)&Bb[buf][0];
#pragma unroll
    for (int kc2 = 0; kc2 < 3; kc2++) {
      const int kc = half * 3 + kc2;
      bf16x8 af[4];
#pragma unroll
      for (int rt = 0; rt < 4; rt++)
        af[rt] = *(const bf16x8*)(vpad + (size_t)gidx[rt] * CINC + kc * 32 + quad * 8);
#pragma unroll
      for (int ct = 0; ct < 6; ct++) {
        bf16x8 bfm = *(const bf16x8*)(bbr + (size_t)(kc2 * 6 + ct) * 1024 + (size_t)lane * 16);
#pragma unroll
        for (int rt = 0; rt < 4; rt++)
          acc[rt][ct] = __builtin_amdgcn_mfma_f32_16x16x32_bf16(af[rt], bfm, acc[rt][ct], 0, 0, 0);
      }
    }
  }

  // epilogue: store fp32 acc (C layout: row = quad*4+rr, col = lane&15)
#pragma unroll
  for (int rt = 0; rt < 4; rt++) {
#pragma unroll
    for (int rr = 0; rr < 4; rr++) {
      const int r2 = rb + rt * 16 + quad * 4 + rr;
      if (r2 < M) {
        float* dst = accbuf + (size_t)r2 * HIDC + m;
#pragma unroll
        for (int ct = 0; ct < 6; ct++) dst[ct * 16] = acc[rt][ct][rr];
      }
    }
  }
  // BN partial sums (rows >= M contributed exact zeros)
#pragma unroll
  for (int ct = 0; ct < 6; ct++) {
    float sv = 0.f, s2 = 0.f;
#pragma unroll
    for (int rt = 0; rt < 4; rt++)
#pragma unroll
      for (int rr = 0; rr < 4; rr++) {
        float v = acc[rt][ct][rr];
        sv += v;
        s2 += v * v;
      }
    sv += __shfl_xor(sv, 16);
    sv += __shfl_xor(sv, 32);
    s2 += __shfl_xor(s2, 16);
    s2 += __shfl_xor(s2, 32);
    if (lane < 16) {
      atomicAdd(bnsum + ct * 16 + lane, sv);
      atomicAdd(bnsum + 96 + ct * 16 + lane, s2);
    }
  }
}

// ---------------------------------------------------------------------------
// K4: finalize BN: scale = gamma*rsqrt(var+eps), shift = beta - mu*scale.
// ---------------------------------------------------------------------------
__global__ void k_bnfin(const float* __restrict__ bnsum, const float* __restrict__ gamma,
                        const float* __restrict__ beta, float* __restrict__ ss, int M) {
  int c = threadIdx.x;
  if (c >= 96) return;
  float inv = 1.0f / (float)M;
  float mu = bnsum[c] * inv;
  float var = bnsum[96 + c] * inv - mu * mu;
  var = fmaxf(var, 0.f);
  float sc = gamma[c] * rsqrtf(var + EPSC);
  ss[c] = sc;
  ss[96 + c] = beta[c] - mu * sc;
}

// ---------------------------------------------------------------------------
// K5: y = relu(acc*scale + shift) -> bf16 ypad, zero pad row M.
// ---------------------------------------------------------------------------
__global__ void k_bnapply(const float* __restrict__ accbuf, const float* __restrict__ ss,
                          bf16* __restrict__ ypad, int M) {
  int t = blockIdx.x * 256 + threadIdx.x;
  if (t >= (M + 1) * HIDC) return;
  int v = t / HIDC;
  int c = t - v * HIDC;
  float y = 0.f;
  if (v < M) y = fmaxf(accbuf[t] * ss[c] + ss[96 + c], 0.f);
  ypad[t] = (bf16)y;
}

// ---------------------------------------------------------------------------
// K6: lin = hx @ W_lin + b_lin (fp32 in, bf16 MFMA, fp32 out)
// ---------------------------------------------------------------------------
__launch_bounds__(384, 2)
__global__ void k_linear(const float* __restrict__ hid, const float* __restrict__ qry,
                         const bf16* __restrict__ wlpack, const float* __restrict__ blin,
                         float* __restrict__ lin, int Npts) {
  __shared__ bf16 Bb[18432];
  const int tid = threadIdx.x;
  const int wave = tid >> 6;
  const int lane = tid & 63;
  const int m = lane & 15;
  const int quad = lane >> 4;
  const int rb = blockIdx.x * 384 + wave * 64;

  {
    const char* src = (const char*)wlpack;
    char* dst = (char*)&Bb[0];
#pragma unroll
    for (int i = 0; i < 6; i++) {
      size_t o = (size_t)(wave * 6 + i) * 1024 + (size_t)lane * 16;
      *(i32x4*)(dst + o) = *(const i32x4*)(src + o);
    }
  }
  __syncthreads();

  f32x4 acc[4][6];
#pragma unroll
  for (int rt = 0; rt < 4; rt++)
#pragma unroll
    for (int ct = 0; ct < 6; ct++) {
      f32x4 z = {0.f, 0.f, 0.f, 0.f};
      acc[rt][ct] = z;
    }

  int prow[4];
#pragma unroll
  for (int rt = 0; rt < 4; rt++) {
    int r = rb + rt * 16 + m;
    prow[rt] = (r < Npts) ? r : (Npts - 1);
  }
  const char* bbr = (const char*)&Bb[0];
#pragma unroll
  for (int kc = 0; kc < 6; kc++) {
    const float* srcA = (kc < 3) ? (hid + kc * 32) : (qry + (kc - 3) * 32);
    bf16x8 af[4];
#pragma unroll
    for (int rt = 0; rt < 4; rt++) {
      const float* pA = srcA + (size_t)prow[rt] * HIDC + quad * 8;
      f32x4 lo = *(const f32x4*)pA;
      f32x4 hi = *(const f32x4*)(pA + 4);
#pragma unroll
      for (int j = 0; j < 4; j++) {
        af[rt][j] = (bf16)lo[j];
        af[rt][4 + j] = (bf16)hi[j];
      }
    }
#pragma unroll
    for (int ct = 0; ct < 6; ct++) {
      bf16x8 bfm = *(const bf16x8*)(bbr + (size_t)(kc * 6 + ct) * 1024 + (size_t)lane * 16);
#pragma unroll
      for (int rt = 0; rt < 4; rt++)
        acc[rt][ct] = __builtin_amdgcn_mfma_f32_16x16x32_bf16(af[rt], bfm, acc[rt][ct], 0, 0, 0);
    }
  }
#pragma unroll
  for (int rt = 0; rt < 4; rt++)
#pragma unroll
    for (int rr = 0; rr < 4; rr++) {
      const int r2 = rb + rt * 16 + quad * 4 + rr;
      if (r2 < Npts) {
        float* dst = lin + (size_t)r2 * HIDC + m;
#pragma unroll
        for (int ct = 0; ct < 6; ct++)
          dst[ct * 16] = acc[rt][ct][rr] + blin[ct * 16 + m];
      }
    }
}

// ---------------------------------------------------------------------------
// K7: out = lin + sum_k w[p,k] * ypad[cidx[p,k]]  (8-channel groups)
// ---------------------------------------------------------------------------
__global__ void k_out(const float* __restrict__ lin, const bf16* __restrict__ ypad,
                      const float* __restrict__ cw, const int* __restrict__ cidx,
                      float* __restrict__ out, int Npts) {
  int t = blockIdx.x * 256 + threadIdx.x;
  if (t >= Npts * 12) return;
  int p = t / 12;
  int g = t - p * 12;
  const float* lp = lin + (size_t)p * HIDC + g * 8;
  float a[8];
  f32x4 l0 = *(const f32x4*)lp;
  f32x4 l1 = *(const f32x4*)(lp + 4);
#pragma unroll
  for (int j = 0; j < 4; j++) { a[j] = l0[j]; a[4 + j] = l1[j]; }
  f32x4 w0 = *(const f32x4*)(cw + (size_t)p * 8);
  f32x4 w1 = *(const f32x4*)(cw + (size_t)p * 8 + 4);
  const i32x4* cp = (const i32x4*)(cidx + (size_t)p * 8);
  i32x4 c0 = cp[0], c1 = cp[1];
#pragma unroll
  for (int k = 0; k < 8; k++) {
    int idx = (k < 4) ? c0[k] : c1[k - 4];
    float wk = (k < 4) ? w0[k] : w1[k - 4];
    bf16x8 yv = *(const bf16x8*)(ypad + (size_t)idx * HIDC + g * 8);
#pragma unroll
    for (int j = 0; j < 8; j++) a[j] += wk * (float)yv[j];
  }
  float* op = out + (size_t)p * HIDC + g * 8;
  f32x4 s0, s1;
#pragma unroll
  for (int j = 0; j < 4; j++) { s0[j] = a[j]; s1[j] = a[4 + j]; }
  *(f32x4*)op = s0;
  *(f32x4*)(op + 4) = s1;
}

// ---------------------------------------------------------------------------
extern "C" void kernel_launch(void* const* d_in, const int* in_sizes, int n_in,
                              void* d_out, int out_size, void* d_ws, size_t ws_size,
                              hipStream_t stream) {
  const float* hid = (const float*)d_in[0];
  const float* qry = (const float*)d_in[1];
  const float* Wc = (const float*)d_in[2];
  const float* gamma = (const float*)d_in[3];
  const float* beta = (const float*)d_in[4];
  const float* Wl = (const float*)d_in[5];
  const float* blin = (const float*)d_in[6];
  const float* cw = (const float*)d_in[7];
  const int* seg = (const int*)d_in[8];
  const int* nbr = (const int*)d_in[9];
  const int* cidx = (const int*)d_in[10];
  float* out = (float*)d_out;
  const int Npts = in_sizes[0] / HIDC;
  const int M = in_sizes[9] / 27;

  // ---- workspace layout with overlays ----
  // regionA: vsum fp32 [M,192] -> accbuf fp32 [M,96] -> lin fp32 [N,96]
  // regionB: vpad bf16 [M+1,192] -> ypad bf16 [M+1,96]
  char* ws = (char*)d_ws;
  size_t cur = 0;
  auto alloc = [&](size_t b) { size_t o = cur; cur = (cur + b + 255) & ~(size_t)255; return o; };
  size_t RA = (size_t)M * CINC * 4;                       // vsum
  size_t need = (size_t)Npts * HIDC * 4;                  // lin
  if (need > RA) RA = need;
  size_t o_A = alloc(RA);
  size_t o_cnt = alloc((size_t)M * 4);
  size_t o_bn = alloc(192 * 4);
  size_t o_ss = alloc(192 * 4);
  size_t o_B = alloc((size_t)(M + 1) * CINC * 2);
  size_t o_wpack = alloc((size_t)28 * 18432 * 2);
  (void)ws_size; (void)n_in; (void)out_size;

  float* vsum = (float*)(ws + o_A);
  float* accbuf = (float*)(ws + o_A);   // after vsum dead (K3..K5)
  float* lin = (float*)(ws + o_A);      // after accbuf dead (K6..K7)
  float* cnt = (float*)(ws + o_cnt);
  float* bnsum = (float*)(ws + o_bn);
  float* ss = (float*)(ws + o_ss);
  bf16* vpad = (bf16*)(ws + o_B);
  bf16* ypad = (bf16*)(ws + o_B);       // after vpad dead (K5..K7)
  bf16* wpack = (bf16*)(ws + o_wpack);
  bf16* wlpack = wpack + (size_t)27 * 18432;

  // zero vsum + cnt + bnsum accumulators (ws is poisoned 0xAA each call)
  hipMemsetAsync(ws, 0, o_bn + 192 * 4, stream);

  int totalRepack = 28 * 18432;
  k_repack<<<(totalRepack + 255) / 256, 256, 0, stream>>>(Wc, Wl, wpack, totalRepack);
  k_voxelize<<<(Npts * CINC + 255) / 256, 256, 0, stream>>>(hid, qry, seg, vsum, cnt, Npts);
  k_vfeat<<<((M + 1) * CINC + 255) / 256, 256, 0, stream>>>(vsum, cnt, vpad, M);
  k_conv<<<(M + 383) / 384, 384, 0, stream>>>(vpad, nbr, wpack, accbuf, bnsum, M);
  k_bnfin<<<1, 128, 0, stream>>>(bnsum, gamma, beta, ss, M);
  k_bnapply<<<((M + 1) * HIDC + 255) / 256, 256, 0, stream>>>(accbuf, ss, ypad, M);
  k_linear<<<(Npts + 383) / 384, 384, 0, stream>>>(hid, qry, wlpack, blin, lin, Npts);
  k_out<<<(Npts * 12 + 255) / 256, 256, 0, stream>>>(lin, ypad, cw, cidx, out, Npts);
}